// Round 1
// baseline (385.599 us; speedup 1.0000x reference)
//
#include <hip/hip_runtime.h>

#define EDGES_PER_BLOCK 4   // 4 waves of 64 per block

__global__ void scatter_add_kernel(const float* __restrict__ gemb,
                                   const float* __restrict__ efeat,
                                   const int*   __restrict__ src,
                                   const int*   __restrict__ dst,
                                   float*       __restrict__ out,
                                   int E) {
    // one 64-lane wave per edge; lane = feature index 0..63
    int eidx = blockIdx.x * EDGES_PER_BLOCK + (threadIdx.x >> 6);
    int lane = threadIdx.x & 63;
    if (eidx >= E) return;

    int s = src[eidx];   // wave-uniform
    int d = dst[eidx];   // wave-uniform

    // coalesced 256B read of the source row
    float v = gemb[(long)s * 64 + lane];

    // scatter-add into destination row (65-wide output)
    atomicAdd(&out[(long)d * 65 + lane], v);
    if (lane == 0) {
        atomicAdd(&out[(long)d * 65 + 64], efeat[eidx]);
    }
}

extern "C" void kernel_launch(void* const* d_in, const int* in_sizes, int n_in,
                              void* d_out, int out_size, void* d_ws, size_t ws_size,
                              hipStream_t stream) {
    const float* gemb  = (const float*)d_in[0];   // [N, 64]
    const float* efeat = (const float*)d_in[1];   // [E]
    const int*   src   = (const int*)d_in[2];     // [E]
    const int*   dst   = (const int*)d_in[3];     // [E]
    float*       out   = (float*)d_out;           // [N, 65]

    int E = in_sizes[1];

    // deterministic: zero the accumulator every call (harness poisons once,
    // never re-poisons between replays)
    hipMemsetAsync(d_out, 0, (size_t)out_size * sizeof(float), stream);

    int blocks = (E + EDGES_PER_BLOCK - 1) / EDGES_PER_BLOCK;
    scatter_add_kernel<<<blocks, EDGES_PER_BLOCK * 64, 0, stream>>>(
        gemb, efeat, src, dst, out, E);
}